// Round 2
// baseline (900.430 us; speedup 1.0000x reference)
//
#include <hip/hip_runtime.h>
#include <math.h>

typedef unsigned short u16;

__device__ inline float bf2f(u16 u) {
    union { unsigned int i; float f; } v;
    v.i = ((unsigned int)u) << 16;
    return v.f;
}
__device__ inline u16 f2bf(float f) {
    union { float f; unsigned int i; } v;
    v.f = f;
    unsigned int b = v.i;
    return (u16)((b + 0x7FFFu + ((b >> 16) & 1u)) >> 16);
}

// ---------------- CSR build ----------------

__global__ void k_zero_int(int* __restrict__ p, int n) {
    int i = blockIdx.x * blockDim.x + threadIdx.x;
    if (i < n) p[i] = 0;
}

__global__ void k_count(const int* __restrict__ ei, int* __restrict__ cnt, int E) {
    int e = blockIdx.x * blockDim.x + threadIdx.x;
    if (e < E) atomicAdd(&cnt[ei[E + e]], 1);
}

// per-block (512 elems) partial sums
__global__ __launch_bounds__(256) void k_partial(const int* __restrict__ cnt,
                                                 int* __restrict__ partials, int n) {
    __shared__ int sdata[256];
    int base = blockIdx.x * 512;
    int t = threadIdx.x;
    int v = 0;
    if (base + t < n) v += cnt[base + t];
    if (base + 256 + t < n) v += cnt[base + 256 + t];
    sdata[t] = v;
    __syncthreads();
    for (int s = 128; s > 0; s >>= 1) {
        if (t < s) sdata[t] += sdata[t + s];
        __syncthreads();
    }
    if (t == 0) partials[blockIdx.x] = sdata[0];
}

// single-block exclusive scan of partials (nb <= 256)
__global__ __launch_bounds__(256) void k_scan_top(const int* __restrict__ partials,
                                                  int* __restrict__ blkoff, int nb) {
    __shared__ int lds[256];
    int t = threadIdx.x;
    int v = (t < nb) ? partials[t] : 0;
    lds[t] = v;
    __syncthreads();
    for (int off = 1; off < 256; off <<= 1) {
        int x = lds[t];
        int y = (t >= off) ? lds[t - off] : 0;
        __syncthreads();
        lds[t] = x + y;
        __syncthreads();
    }
    if (t < nb) blkoff[t] = lds[t] - v;   // exclusive
}

// per-block local scan + add block offset -> row_ptr, cursor, dinv
__global__ __launch_bounds__(512) void k_apply(const int* __restrict__ cnt,
                                               const int* __restrict__ blkoff,
                                               int* __restrict__ row_ptr,
                                               int* __restrict__ cursor,
                                               float* __restrict__ dinv,
                                               int n, int Etot) {
    __shared__ int lds[512];
    int b = blockIdx.x, t = threadIdx.x;
    int i = b * 512 + t;
    int v = (i < n) ? cnt[i] : 0;
    lds[t] = v;
    __syncthreads();
    for (int off = 1; off < 512; off <<= 1) {
        int x = lds[t];
        int y = (t >= off) ? lds[t - off] : 0;
        __syncthreads();
        lds[t] = x + y;
        __syncthreads();
    }
    if (i < n) {
        int excl = blkoff[b] + lds[t] - v;
        row_ptr[i] = excl;
        cursor[i] = excl;
        dinv[i] = rsqrtf((float)v + 1.0f);
    }
    if (i == 0) row_ptr[n] = Etot;
}

__global__ void k_scatter(const int* __restrict__ ei, int* __restrict__ cursor,
                          int* __restrict__ csr_src, float* __restrict__ csr_coef,
                          const float* __restrict__ dinv, int E) {
    int e = blockIdx.x * blockDim.x + threadIdx.x;
    if (e < E) {
        int s = ei[e];
        int d = ei[E + e];
        int pos = atomicAdd(&cursor[d], 1);
        csr_src[pos] = s;
        csr_coef[pos] = dinv[s] * dinv[d];
    }
}

// ---------------- BN fold ----------------
__global__ void k_bnfold(const float* __restrict__ b, const float* __restrict__ g,
                         const float* __restrict__ be, const float* __restrict__ m,
                         const float* __restrict__ v, float* __restrict__ s,
                         float* __restrict__ t, int H) {
    int i = blockIdx.x * blockDim.x + threadIdx.x;
    if (i < H) {
        float sc = g[i] * rsqrtf(v[i] + 1e-5f);
        s[i] = sc;
        t[i] = (b[i] - m[i]) * sc + be[i];
    }
}

// ---------------- GEMM: C[M,F] = A_bf16[M,K] @ B_f32[K,F] ----------------
// BM=64, BN=64, BK=16, 256 threads, 4x4 register blocking.
// mode 1: BN(scale s, shift t) + ReLU, store bf16.  mode 0: plain, store f32.
__global__ __launch_bounds__(256) void g_gemm(const u16* __restrict__ A,
                                              const float* __restrict__ B,
                                              void* __restrict__ Cv,
                                              int M, int K, int F,
                                              const float* __restrict__ s,
                                              const float* __restrict__ t,
                                              int mode) {
    __shared__ float As[64][17];
    __shared__ float Bs[16][64];
    int tid = threadIdx.x;
    int tx = tid & 15, ty = tid >> 4;
    int row0 = blockIdx.x * 64;
    int col0 = blockIdx.y * 64;

    float acc[4][4] = {{0.f}};

    for (int k0 = 0; k0 < K; k0 += 16) {
        // A tile: thread -> row r = tid>>2, kq = (tid&3)*4, 4 bf16 = 8 bytes
        {
            int r = tid >> 2, kq = (tid & 3) << 2;
            int gr = row0 + r;
            float a0 = 0.f, a1 = 0.f, a2 = 0.f, a3 = 0.f;
            if (gr < M) {
                ushort4 u = *(const ushort4*)(A + (size_t)gr * K + k0 + kq);
                a0 = bf2f(u.x); a1 = bf2f(u.y); a2 = bf2f(u.z); a3 = bf2f(u.w);
            }
            As[r][kq + 0] = a0;
            As[r][kq + 1] = a1;
            As[r][kq + 2] = a2;
            As[r][kq + 3] = a3;
        }
        // B tile: kb = tid>>4, cq = (tid&15)*4
        {
            int kb = tid >> 4, cq = (tid & 15) << 2;
            float4 bv = make_float4(0.f, 0.f, 0.f, 0.f);
            if (col0 + cq < F) bv = *(const float4*)(B + (size_t)(k0 + kb) * F + col0 + cq);
            *(float4*)&Bs[kb][cq] = bv;
        }
        __syncthreads();

        #pragma unroll
        for (int k = 0; k < 16; ++k) {
            float a[4], bb[4];
            #pragma unroll
            for (int i = 0; i < 4; ++i) a[i] = As[ty * 4 + i][k];
            #pragma unroll
            for (int j = 0; j < 4; ++j) bb[j] = Bs[k][tx * 4 + j];
            #pragma unroll
            for (int i = 0; i < 4; ++i)
                #pragma unroll
                for (int j = 0; j < 4; ++j)
                    acc[i][j] += a[i] * bb[j];
        }
        __syncthreads();
    }

    int gcbase = col0 + tx * 4;
    if (gcbase + 3 >= F) return;
    #pragma unroll
    for (int i = 0; i < 4; ++i) {
        int gr = row0 + ty * 4 + i;
        if (gr >= M) continue;
        if (mode == 1) {
            u16* C = (u16*)Cv;
            ushort4 o;
            float v0 = fmaxf(acc[i][0] * s[gcbase + 0] + t[gcbase + 0], 0.f);
            float v1 = fmaxf(acc[i][1] * s[gcbase + 1] + t[gcbase + 1], 0.f);
            float v2 = fmaxf(acc[i][2] * s[gcbase + 2] + t[gcbase + 2], 0.f);
            float v3 = fmaxf(acc[i][3] * s[gcbase + 3] + t[gcbase + 3], 0.f);
            o.x = f2bf(v0); o.y = f2bf(v1); o.z = f2bf(v2); o.w = f2bf(v3);
            *(ushort4*)(C + (size_t)gr * F + gcbase) = o;
        } else {
            float* C = (float*)Cv;
            float4 o;
            o.x = acc[i][0]; o.y = acc[i][1]; o.z = acc[i][2]; o.w = acc[i][3];
            *(float4*)(C + (size_t)gr * F + gcbase) = o;
        }
    }
}

// ---------------- Aggregation kernels (1 wave = 1 node) ----------------
// Layer 1: F=128, f32 in, bf16 out. Each lane owns 2 features.
__global__ __launch_bounds__(256) void agg_x(const float* __restrict__ in,
                                             u16* __restrict__ outp,
                                             const int* __restrict__ row_ptr,
                                             const int* __restrict__ csr_src,
                                             const float* __restrict__ csr_coef,
                                             const float* __restrict__ dinv,
                                             int nnodes) {
    int wave = threadIdx.x >> 6;
    int lane = threadIdx.x & 63;
    int node = blockIdx.x * 4 + wave;
    if (node >= nnodes) return;
    int off = lane * 2;
    float d = dinv[node];
    float dd = d * d;
    float2 self = *(const float2*)(in + (size_t)node * 128 + off);
    float accx = self.x * dd, accy = self.y * dd;
    int e0 = row_ptr[node], e1 = row_ptr[node + 1];
    for (int e = e0; e < e1; ++e) {
        int srcn = csr_src[e];
        float c = csr_coef[e];
        float2 vv = *(const float2*)(in + (size_t)srcn * 128 + off);
        accx += c * vv.x;
        accy += c * vv.y;
    }
    unsigned int pk = (unsigned int)f2bf(accx) | ((unsigned int)f2bf(accy) << 16);
    *(unsigned int*)(outp + (size_t)node * 128 + off) = pk;
}

// Layer 2: F=256, bf16 in/out. Each lane owns 4 features.
__global__ __launch_bounds__(256) void agg_h(const u16* __restrict__ in,
                                             u16* __restrict__ outp,
                                             const int* __restrict__ row_ptr,
                                             const int* __restrict__ csr_src,
                                             const float* __restrict__ csr_coef,
                                             const float* __restrict__ dinv,
                                             int nnodes) {
    int wave = threadIdx.x >> 6;
    int lane = threadIdx.x & 63;
    int node = blockIdx.x * 4 + wave;
    if (node >= nnodes) return;
    int off = lane * 4;
    float d = dinv[node];
    float dd = d * d;
    ushort4 u = *(const ushort4*)(in + (size_t)node * 256 + off);
    float ax = bf2f(u.x) * dd, ay = bf2f(u.y) * dd, az = bf2f(u.z) * dd, aw = bf2f(u.w) * dd;
    int e0 = row_ptr[node], e1 = row_ptr[node + 1];
    for (int e = e0; e < e1; ++e) {
        int srcn = csr_src[e];
        float c = csr_coef[e];
        ushort4 vv = *(const ushort4*)(in + (size_t)srcn * 256 + off);
        ax += c * bf2f(vv.x);
        ay += c * bf2f(vv.y);
        az += c * bf2f(vv.z);
        aw += c * bf2f(vv.w);
    }
    ushort4 o;
    o.x = f2bf(ax); o.y = f2bf(ay); o.z = f2bf(az); o.w = f2bf(aw);
    *(ushort4*)(outp + (size_t)node * 256 + off) = o;
}

// Layer 3 final: F=32 f32, 32 lanes per node, + b3, sigmoid
__global__ __launch_bounds__(256) void agg32_sig(const float* __restrict__ z,
                                                 float* __restrict__ out,
                                                 const int* __restrict__ row_ptr,
                                                 const int* __restrict__ csr_src,
                                                 const float* __restrict__ csr_coef,
                                                 const float* __restrict__ dinv,
                                                 const float* __restrict__ b3,
                                                 int nnodes) {
    int grp = threadIdx.x >> 5;
    int lane = threadIdx.x & 31;
    int node = blockIdx.x * 8 + grp;
    if (node >= nnodes) return;
    float d = dinv[node];
    float acc = z[(size_t)node * 32 + lane] * d * d;
    int e0 = row_ptr[node], e1 = row_ptr[node + 1];
    for (int e = e0; e < e1; ++e) {
        acc += csr_coef[e] * z[(size_t)csr_src[e] * 32 + lane];
    }
    acc += b3[lane];
    out[(size_t)node * 32 + lane] = 1.f / (1.f + expf(-acc));
}

// ---------------- launch ----------------

extern "C" void kernel_launch(void* const* d_in, const int* in_sizes, int n_in,
                              void* d_out, int out_size, void* d_ws, size_t ws_size,
                              hipStream_t stream) {
    const float* x  = (const float*)d_in[0];
    const int*   ei = (const int*)d_in[1];      // int32 on device
    const float* W1 = (const float*)d_in[2];
    const float* b1 = (const float*)d_in[3];
    const float* g1 = (const float*)d_in[4];
    const float* be1 = (const float*)d_in[5];
    const float* m1 = (const float*)d_in[6];
    const float* v1 = (const float*)d_in[7];
    const float* W2 = (const float*)d_in[8];
    const float* b2 = (const float*)d_in[9];
    const float* g2 = (const float*)d_in[10];
    const float* be2 = (const float*)d_in[11];
    const float* m2 = (const float*)d_in[12];
    const float* v2 = (const float*)d_in[13];
    const float* W3 = (const float*)d_in[14];
    const float* b3 = (const float*)d_in[15];
    float* out = (float*)d_out;

    const int N = in_sizes[0] / 128;   // 100000
    const int E = in_sizes[1] / 2;     // 1600000

    // workspace carve-up
    char* w = (char*)d_ws;
    auto alloc = [&](size_t bytes) -> void* {
        void* p = (void*)w;
        w += (bytes + 255) & ~(size_t)255;
        return p;
    };
    int* cnt      = (int*)alloc((size_t)N * 4);
    int* row_ptr  = (int*)alloc((size_t)(N + 1) * 4);
    int* cursor   = (int*)alloc((size_t)N * 4);
    float* dinv   = (float*)alloc((size_t)N * 4);
    int* partials = (int*)alloc(256 * 4);
    int* blkoff   = (int*)alloc(256 * 4);
    float* s1 = (float*)alloc(256 * 4);
    float* t1 = (float*)alloc(256 * 4);
    float* s2 = (float*)alloc(256 * 4);
    float* t2 = (float*)alloc(256 * 4);
    int* csr_src    = (int*)alloc((size_t)E * 4);
    float* csr_coef = (float*)alloc((size_t)E * 4);
    u16* bufA = (u16*)alloc((size_t)N * 256 * 2);   // xa (N,128) then h1a (N,256)
    u16* bufB = (u16*)alloc((size_t)N * 256 * 2);   // h1 then h2
    float* z3 = (float*)bufA;  // N*32 f32 = 12.8MB, bufA free by then (h1a dead)

    int nb = (N + 511) / 512;

    // CSR build
    k_zero_int<<<(N + 255) / 256, 256, 0, stream>>>(cnt, N);
    k_count<<<(E + 255) / 256, 256, 0, stream>>>(ei, cnt, E);
    k_partial<<<nb, 256, 0, stream>>>(cnt, partials, N);
    k_scan_top<<<1, 256, 0, stream>>>(partials, blkoff, nb);
    k_apply<<<nb, 512, 0, stream>>>(cnt, blkoff, row_ptr, cursor, dinv, N, E);
    k_scatter<<<(E + 255) / 256, 256, 0, stream>>>(ei, cursor, csr_src, csr_coef, dinv, E);

    // BN folds
    k_bnfold<<<1, 256, 0, stream>>>(b1, g1, be1, m1, v1, s1, t1, 256);
    k_bnfold<<<1, 256, 0, stream>>>(b2, g2, be2, m2, v2, s2, t2, 256);

    // Layer 1: aggregate x (128) then GEMM(128->256) + BN + ReLU -> bf16
    agg_x<<<(N + 3) / 4, 256, 0, stream>>>(x, bufA, row_ptr, csr_src, csr_coef, dinv, N);
    g_gemm<<<dim3((N + 63) / 64, 4), 256, 0, stream>>>(bufA, W1, bufB, N, 128, 256, s1, t1, 1);

    // Layer 2: aggregate h1 (256) then GEMM(256->256) + BN + ReLU -> bf16
    agg_h<<<(N + 3) / 4, 256, 0, stream>>>(bufB, bufA, row_ptr, csr_src, csr_coef, dinv, N);
    g_gemm<<<dim3((N + 63) / 64, 4), 256, 0, stream>>>(bufA, W2, bufB, N, 256, 256, s2, t2, 1);

    // Layer 3: GEMM(256->32) -> f32, then aggregate(32) + b3 + sigmoid
    g_gemm<<<dim3((N + 63) / 64, 1), 256, 0, stream>>>(bufB, W3, (void*)z3, N, 256, 32,
                                                       (const float*)nullptr, (const float*)nullptr, 0);
    agg32_sig<<<(N + 7) / 8, 256, 0, stream>>>(z3, out, row_ptr, csr_src, csr_coef, dinv, b3, N);
}

// Round 3
// 807.992 us; speedup vs baseline: 1.1144x; 1.1144x over previous
//
#include <hip/hip_runtime.h>
#include <math.h>

typedef unsigned short u16;
typedef __attribute__((ext_vector_type(8))) __bf16 bfx8;
typedef __attribute__((ext_vector_type(4))) float f32x4;

__device__ inline float bf2f(u16 u) {
    union { unsigned int i; float f; } v;
    v.i = ((unsigned int)u) << 16;
    return v.f;
}
__device__ inline u16 f2bf(float f) {
    union { float f; unsigned int i; } v;
    v.f = f;
    unsigned int b = v.i;
    return (u16)((b + 0x7FFFu + ((b >> 16) & 1u)) >> 16);
}

// ---------------- CSR build ----------------

__global__ void k_zero_int(int* __restrict__ p, int n) {
    int i = blockIdx.x * blockDim.x + threadIdx.x;
    if (i < n) p[i] = 0;
}

__global__ void k_count(const int* __restrict__ ei, int* __restrict__ cnt, int E) {
    int e = blockIdx.x * blockDim.x + threadIdx.x;
    if (e < E) atomicAdd(&cnt[ei[E + e]], 1);
}

__global__ __launch_bounds__(256) void k_partial(const int* __restrict__ cnt,
                                                 int* __restrict__ partials, int n) {
    __shared__ int sdata[256];
    int base = blockIdx.x * 512;
    int t = threadIdx.x;
    int v = 0;
    if (base + t < n) v += cnt[base + t];
    if (base + 256 + t < n) v += cnt[base + 256 + t];
    sdata[t] = v;
    __syncthreads();
    for (int s = 128; s > 0; s >>= 1) {
        if (t < s) sdata[t] += sdata[t + s];
        __syncthreads();
    }
    if (t == 0) partials[blockIdx.x] = sdata[0];
}

__global__ __launch_bounds__(256) void k_scan_top(const int* __restrict__ partials,
                                                  int* __restrict__ blkoff, int nb) {
    __shared__ int lds[256];
    int t = threadIdx.x;
    int v = (t < nb) ? partials[t] : 0;
    lds[t] = v;
    __syncthreads();
    for (int off = 1; off < 256; off <<= 1) {
        int x = lds[t];
        int y = (t >= off) ? lds[t - off] : 0;
        __syncthreads();
        lds[t] = x + y;
        __syncthreads();
    }
    if (t < nb) blkoff[t] = lds[t] - v;   // exclusive
}

__global__ __launch_bounds__(512) void k_apply(const int* __restrict__ cnt,
                                               const int* __restrict__ blkoff,
                                               int* __restrict__ row_ptr,
                                               int* __restrict__ cursor,
                                               float* __restrict__ dinv,
                                               int n, int Etot) {
    __shared__ int lds[512];
    int b = blockIdx.x, t = threadIdx.x;
    int i = b * 512 + t;
    int v = (i < n) ? cnt[i] : 0;
    lds[t] = v;
    __syncthreads();
    for (int off = 1; off < 512; off <<= 1) {
        int x = lds[t];
        int y = (t >= off) ? lds[t - off] : 0;
        __syncthreads();
        lds[t] = x + y;
        __syncthreads();
    }
    if (i < n) {
        int excl = blkoff[b] + lds[t] - v;
        row_ptr[i] = excl;
        cursor[i] = excl;
        dinv[i] = rsqrtf((float)v + 1.0f);
    }
    if (i == 0) row_ptr[n] = Etot;
}

__global__ void k_scatter(const int* __restrict__ ei, int* __restrict__ cursor,
                          int* __restrict__ csr_src, float* __restrict__ csr_coef,
                          const float* __restrict__ dinv, int E) {
    int e = blockIdx.x * blockDim.x + threadIdx.x;
    if (e < E) {
        int s = ei[e];
        int d = ei[E + e];
        int pos = atomicAdd(&cursor[d], 1);
        csr_src[pos] = s;
        csr_coef[pos] = dinv[s] * dinv[d];
    }
}

// ---------------- small converts ----------------

__global__ void k_bnfold(const float* __restrict__ b, const float* __restrict__ g,
                         const float* __restrict__ be, const float* __restrict__ m,
                         const float* __restrict__ v, float* __restrict__ s,
                         float* __restrict__ t, int H) {
    int i = blockIdx.x * blockDim.x + threadIdx.x;
    if (i < H) {
        float sc = g[i] * rsqrtf(v[i] + 1e-5f);
        s[i] = sc;
        t[i] = (b[i] - m[i]) * sc + be[i];
    }
}

// W[K,F] f32 -> Wt[F,K] bf16
__global__ void k_w2bf(const float* __restrict__ W, u16* __restrict__ Wt, int K, int F) {
    int i = blockIdx.x * blockDim.x + threadIdx.x;
    if (i < K * F) {
        int k = i / F, f = i % F;
        Wt[(size_t)f * K + k] = f2bf(W[i]);
    }
}

// x f32 -> bf16 (vectorized: float4 -> ushort4)
__global__ void k_x2bf(const float* __restrict__ x, u16* __restrict__ xb, int n4) {
    int i = blockIdx.x * blockDim.x + threadIdx.x;
    if (i < n4) {
        float4 v = *(const float4*)(x + (size_t)i * 4);
        ushort4 o;
        o.x = f2bf(v.x); o.y = f2bf(v.y); o.z = f2bf(v.z); o.w = f2bf(v.w);
        *(ushort4*)(xb + (size_t)i * 4) = o;
    }
}

// ---------------- MFMA GEMM: C[M,Ftot] = A_bf16[M,K] @ Wt_bf16[Ftot,K]^T ---
// No LDS: fragment loads direct from global (lanes {l,l+16,l+32,l+48} cover
// 64 contiguous bytes of one row). 256 threads = 4 waves; block tile 64 x FT;
// wave w owns rows [w*16, w*16+16) x FT cols.
// MODE 1: BN scale/shift + ReLU, bf16 store.  MODE 0: plain f32 store.
template<int K, int FT, int MODE>
__global__ __launch_bounds__(256) void g_mfma(const u16* __restrict__ A,
                                              const u16* __restrict__ Wt,
                                              void* __restrict__ Cv, int M, int Ftot,
                                              const float* __restrict__ s,
                                              const float* __restrict__ t) {
    int tid = threadIdx.x;
    int w = tid >> 6, l = tid & 63;
    int row0 = blockIdx.x * 64;
    int col0 = blockIdx.y * FT;
    int lr = l & 15;           // row-in-fragment / col-in-fragment
    int koff = (l >> 4) * 8;   // k sub-offset

    int arow = row0 + w * 16 + lr;
    int arow_ld = (arow < M) ? arow : 0;
    const u16* ap = A + (size_t)arow_ld * K + koff;
    const u16* wp = Wt + (size_t)(col0 + lr) * K + koff;

    constexpr int NF = FT / 16;
    f32x4 acc[NF];
    #pragma unroll
    for (int c = 0; c < NF; ++c) acc[c] = (f32x4){0.f, 0.f, 0.f, 0.f};

    #pragma unroll
    for (int kk = 0; kk < K / 32; ++kk) {
        bfx8 af = *(const bfx8*)(ap + kk * 32);
        #pragma unroll
        for (int c = 0; c < NF; ++c) {
            bfx8 bf = *(const bfx8*)(wp + (size_t)c * 16 * K + kk * 32);
            acc[c] = __builtin_amdgcn_mfma_f32_16x16x32_bf16(af, bf, acc[c], 0, 0, 0);
        }
    }

    int orow = row0 + w * 16 + (l >> 4) * 4;
    if (MODE == 1) {
        u16* C = (u16*)Cv;
        #pragma unroll
        for (int c = 0; c < NF; ++c) {
            int gc = col0 + c * 16 + lr;
            float sc = s[gc], tc = t[gc];
            #pragma unroll
            for (int r = 0; r < 4; ++r) {
                int gr = orow + r;
                if (gr < M)
                    C[(size_t)gr * Ftot + gc] = f2bf(fmaxf(acc[c][r] * sc + tc, 0.f));
            }
        }
    } else {
        float* C = (float*)Cv;
        #pragma unroll
        for (int c = 0; c < NF; ++c) {
            int gc = col0 + c * 16 + lr;
            #pragma unroll
            for (int r = 0; r < 4; ++r) {
                int gr = orow + r;
                if (gr < M) C[(size_t)gr * Ftot + gc] = acc[c][r];
            }
        }
    }
}

// ---------------- Aggregation (1 wave = 1 node) ----------------
// F=128 bf16 in/out: lane owns 2 features (u32 load)
__global__ __launch_bounds__(256) void agg_x(const u16* __restrict__ in,
                                             u16* __restrict__ outp,
                                             const int* __restrict__ row_ptr,
                                             const int* __restrict__ csr_src,
                                             const float* __restrict__ csr_coef,
                                             const float* __restrict__ dinv,
                                             int nnodes) {
    int wave = threadIdx.x >> 6;
    int lane = threadIdx.x & 63;
    int node = blockIdx.x * 4 + wave;
    if (node >= nnodes) return;
    int off = lane * 2;
    float d = dinv[node];
    float dd = d * d;
    unsigned int su = *(const unsigned int*)(in + (size_t)node * 128 + off);
    float ax = bf2f((u16)(su & 0xffff)) * dd;
    float ay = bf2f((u16)(su >> 16)) * dd;
    int e0 = row_ptr[node], e1 = row_ptr[node + 1];
    for (int e = e0; e < e1; ++e) {
        int srcn = csr_src[e];
        float c = csr_coef[e];
        unsigned int u = *(const unsigned int*)(in + (size_t)srcn * 128 + off);
        ax += c * bf2f((u16)(u & 0xffff));
        ay += c * bf2f((u16)(u >> 16));
    }
    unsigned int pk = (unsigned int)f2bf(ax) | ((unsigned int)f2bf(ay) << 16);
    *(unsigned int*)(outp + (size_t)node * 128 + off) = pk;
}

// F=256 bf16 in/out: lane owns 4 features (ushort4)
__global__ __launch_bounds__(256) void agg_h(const u16* __restrict__ in,
                                             u16* __restrict__ outp,
                                             const int* __restrict__ row_ptr,
                                             const int* __restrict__ csr_src,
                                             const float* __restrict__ csr_coef,
                                             const float* __restrict__ dinv,
                                             int nnodes) {
    int wave = threadIdx.x >> 6;
    int lane = threadIdx.x & 63;
    int node = blockIdx.x * 4 + wave;
    if (node >= nnodes) return;
    int off = lane * 4;
    float d = dinv[node];
    float dd = d * d;
    ushort4 u = *(const ushort4*)(in + (size_t)node * 256 + off);
    float ax = bf2f(u.x) * dd, ay = bf2f(u.y) * dd, az = bf2f(u.z) * dd, aw = bf2f(u.w) * dd;
    int e0 = row_ptr[node], e1 = row_ptr[node + 1];
    for (int e = e0; e < e1; ++e) {
        int srcn = csr_src[e];
        float c = csr_coef[e];
        ushort4 vv = *(const ushort4*)(in + (size_t)srcn * 256 + off);
        ax += c * bf2f(vv.x);
        ay += c * bf2f(vv.y);
        az += c * bf2f(vv.z);
        aw += c * bf2f(vv.w);
    }
    ushort4 o;
    o.x = f2bf(ax); o.y = f2bf(ay); o.z = f2bf(az); o.w = f2bf(aw);
    *(ushort4*)(outp + (size_t)node * 256 + off) = o;
}

// F=32 f32: 32 lanes per node, + b3, sigmoid
__global__ __launch_bounds__(256) void agg32_sig(const float* __restrict__ z,
                                                 float* __restrict__ out,
                                                 const int* __restrict__ row_ptr,
                                                 const int* __restrict__ csr_src,
                                                 const float* __restrict__ csr_coef,
                                                 const float* __restrict__ dinv,
                                                 const float* __restrict__ b3,
                                                 int nnodes) {
    int grp = threadIdx.x >> 5;
    int lane = threadIdx.x & 31;
    int node = blockIdx.x * 8 + grp;
    if (node >= nnodes) return;
    float d = dinv[node];
    float acc = z[(size_t)node * 32 + lane] * d * d;
    int e0 = row_ptr[node], e1 = row_ptr[node + 1];
    for (int e = e0; e < e1; ++e) {
        acc += csr_coef[e] * z[(size_t)csr_src[e] * 32 + lane];
    }
    acc += b3[lane];
    out[(size_t)node * 32 + lane] = 1.f / (1.f + expf(-acc));
}

// ---------------- launch ----------------

extern "C" void kernel_launch(void* const* d_in, const int* in_sizes, int n_in,
                              void* d_out, int out_size, void* d_ws, size_t ws_size,
                              hipStream_t stream) {
    const float* x  = (const float*)d_in[0];
    const int*   ei = (const int*)d_in[1];
    const float* W1 = (const float*)d_in[2];
    const float* b1 = (const float*)d_in[3];
    const float* g1 = (const float*)d_in[4];
    const float* be1 = (const float*)d_in[5];
    const float* m1 = (const float*)d_in[6];
    const float* v1 = (const float*)d_in[7];
    const float* W2 = (const float*)d_in[8];
    const float* b2 = (const float*)d_in[9];
    const float* g2 = (const float*)d_in[10];
    const float* be2 = (const float*)d_in[11];
    const float* m2 = (const float*)d_in[12];
    const float* v2 = (const float*)d_in[13];
    const float* W3 = (const float*)d_in[14];
    const float* b3 = (const float*)d_in[15];
    float* out = (float*)d_out;

    const int N = in_sizes[0] / 128;   // 100000
    const int E = in_sizes[1] / 2;     // 1600000

    char* w = (char*)d_ws;
    auto alloc = [&](size_t bytes) -> void* {
        void* p = (void*)w;
        w += (bytes + 255) & ~(size_t)255;
        return p;
    };
    int* cnt      = (int*)alloc((size_t)N * 4);
    int* row_ptr  = (int*)alloc((size_t)(N + 1) * 4);
    int* cursor   = (int*)alloc((size_t)N * 4);
    float* dinv   = (float*)alloc((size_t)N * 4);
    int* partials = (int*)alloc(256 * 4);
    int* blkoff   = (int*)alloc(256 * 4);
    float* s1 = (float*)alloc(256 * 4);
    float* t1 = (float*)alloc(256 * 4);
    float* s2 = (float*)alloc(256 * 4);
    float* t2 = (float*)alloc(256 * 4);
    u16* Wt1 = (u16*)alloc((size_t)128 * 256 * 2);
    u16* Wt2 = (u16*)alloc((size_t)256 * 256 * 2);
    u16* Wt3 = (u16*)alloc((size_t)256 * 32 * 2);
    int* csr_src    = (int*)alloc((size_t)E * 4);
    float* csr_coef = (float*)alloc((size_t)E * 4);
    u16* xbf  = (u16*)alloc((size_t)N * 128 * 2);   // x bf16; reused as z3 later
    u16* bufA = (u16*)alloc((size_t)N * 256 * 2);   // xa (N,128) then h1a (N,256)
    u16* bufB = (u16*)alloc((size_t)N * 256 * 2);   // h1 then h2
    float* z3 = (float*)xbf;                        // N*32 f32 = 12.8MB <= 25.6MB

    int nb = (N + 511) / 512;
    int gx = (N + 63) / 64;

    // CSR build
    k_zero_int<<<(N + 255) / 256, 256, 0, stream>>>(cnt, N);
    k_count<<<(E + 255) / 256, 256, 0, stream>>>(ei, cnt, E);
    k_partial<<<nb, 256, 0, stream>>>(cnt, partials, N);
    k_scan_top<<<1, 256, 0, stream>>>(partials, blkoff, nb);
    k_apply<<<nb, 512, 0, stream>>>(cnt, blkoff, row_ptr, cursor, dinv, N, E);
    k_scatter<<<(E + 255) / 256, 256, 0, stream>>>(ei, cursor, csr_src, csr_coef, dinv, E);

    // param prep
    k_bnfold<<<1, 256, 0, stream>>>(b1, g1, be1, m1, v1, s1, t1, 256);
    k_bnfold<<<1, 256, 0, stream>>>(b2, g2, be2, m2, v2, s2, t2, 256);
    k_w2bf<<<(128 * 256 + 255) / 256, 256, 0, stream>>>(W1, Wt1, 128, 256);
    k_w2bf<<<(256 * 256 + 255) / 256, 256, 0, stream>>>(W2, Wt2, 256, 256);
    k_w2bf<<<(256 * 32 + 255) / 256, 256, 0, stream>>>(W3, Wt3, 256, 32);
    k_x2bf<<<(N * 128 / 4 + 255) / 256, 256, 0, stream>>>(x, xbf, N * 128 / 4);

    // Layer 1: aggregate x(bf16,128) -> GEMM(128->256)+BN+ReLU -> bf16
    agg_x<<<(N + 3) / 4, 256, 0, stream>>>(xbf, bufA, row_ptr, csr_src, csr_coef, dinv, N);
    g_mfma<128, 64, 1><<<dim3(gx, 4), 256, 0, stream>>>(bufA, Wt1, bufB, N, 256, s1, t1);

    // Layer 2: aggregate h1(256) -> GEMM(256->256)+BN+ReLU -> bf16
    agg_h<<<(N + 3) / 4, 256, 0, stream>>>(bufB, bufA, row_ptr, csr_src, csr_coef, dinv, N);
    g_mfma<256, 64, 1><<<dim3(gx, 4), 256, 0, stream>>>(bufA, Wt2, bufB, N, 256, s2, t2);

    // Layer 3: GEMM(256->32) -> f32, then aggregate(32) + b3 + sigmoid
    g_mfma<256, 32, 0><<<dim3(gx, 1), 256, 0, stream>>>(bufB, Wt3, (void*)z3, N, 32,
                                                        (const float*)nullptr,
                                                        (const float*)nullptr);
    agg32_sig<<<(N + 7) / 8, 256, 0, stream>>>(z3, out, row_ptr, csr_src, csr_coef, dinv, b3, N);
}

// Round 4
// 654.939 us; speedup vs baseline: 1.3748x; 1.2337x over previous
//
#include <hip/hip_runtime.h>
#include <math.h>

typedef unsigned short u16;
typedef __attribute__((ext_vector_type(8))) __bf16 bfx8;
typedef __attribute__((ext_vector_type(4))) float f32x4;
typedef __attribute__((ext_vector_type(8))) unsigned short us8;
typedef __attribute__((ext_vector_type(4))) unsigned short us4;

__device__ inline float bf2f(u16 u) {
    union { unsigned int i; float f; } v;
    v.i = ((unsigned int)u) << 16;
    return v.f;
}
__device__ inline u16 f2bf(float f) {
    union { float f; unsigned int i; } v;
    v.f = f;
    unsigned int b = v.i;
    return (u16)((b + 0x7FFFu + ((b >> 16) & 1u)) >> 16);
}

// ---------------- CSR build ----------------

__global__ void k_zero_int(int* __restrict__ p, int n) {
    int i = blockIdx.x * blockDim.x + threadIdx.x;
    if (i < n) p[i] = 0;
}

__global__ void k_count(const int* __restrict__ ei, int* __restrict__ cnt, int E) {
    int e = blockIdx.x * blockDim.x + threadIdx.x;
    if (e < E) atomicAdd(&cnt[ei[E + e]], 1);
}

__global__ __launch_bounds__(256) void k_partial(const int* __restrict__ cnt,
                                                 int* __restrict__ partials, int n) {
    __shared__ int sdata[256];
    int base = blockIdx.x * 512;
    int t = threadIdx.x;
    int v = 0;
    if (base + t < n) v += cnt[base + t];
    if (base + 256 + t < n) v += cnt[base + 256 + t];
    sdata[t] = v;
    __syncthreads();
    for (int s = 128; s > 0; s >>= 1) {
        if (t < s) sdata[t] += sdata[t + s];
        __syncthreads();
    }
    if (t == 0) partials[blockIdx.x] = sdata[0];
}

__global__ __launch_bounds__(256) void k_scan_top(const int* __restrict__ partials,
                                                  int* __restrict__ blkoff, int nb) {
    __shared__ int lds[256];
    int t = threadIdx.x;
    int v = (t < nb) ? partials[t] : 0;
    lds[t] = v;
    __syncthreads();
    for (int off = 1; off < 256; off <<= 1) {
        int x = lds[t];
        int y = (t >= off) ? lds[t - off] : 0;
        __syncthreads();
        lds[t] = x + y;
        __syncthreads();
    }
    if (t < nb) blkoff[t] = lds[t] - v;   // exclusive
}

__global__ __launch_bounds__(512) void k_apply(const int* __restrict__ cnt,
                                               const int* __restrict__ blkoff,
                                               int* __restrict__ row_ptr,
                                               int* __restrict__ cursor,
                                               float* __restrict__ dinv,
                                               int n, int Etot) {
    __shared__ int lds[512];
    int b = blockIdx.x, t = threadIdx.x;
    int i = b * 512 + t;
    int v = (i < n) ? cnt[i] : 0;
    lds[t] = v;
    __syncthreads();
    for (int off = 1; off < 512; off <<= 1) {
        int x = lds[t];
        int y = (t >= off) ? lds[t - off] : 0;
        __syncthreads();
        lds[t] = x + y;
        __syncthreads();
    }
    if (i < n) {
        int excl = blkoff[b] + lds[t] - v;
        row_ptr[i] = excl;
        cursor[i] = excl;
        dinv[i] = rsqrtf((float)v + 1.0f);
    }
    if (i == 0) row_ptr[n] = Etot;
}

__global__ void k_scatter(const int* __restrict__ ei, int* __restrict__ cursor,
                          int* __restrict__ csr_src, float* __restrict__ csr_coef,
                          const float* __restrict__ dinv, int E) {
    int e = blockIdx.x * blockDim.x + threadIdx.x;
    if (e < E) {
        int s = ei[e];
        int d = ei[E + e];
        int pos = atomicAdd(&cursor[d], 1);
        csr_src[pos] = s;
        csr_coef[pos] = dinv[s] * dinv[d];
    }
}

// ---------------- small converts ----------------

__global__ void k_bnfold(const float* __restrict__ b, const float* __restrict__ g,
                         const float* __restrict__ be, const float* __restrict__ m,
                         const float* __restrict__ v, float* __restrict__ s,
                         float* __restrict__ t, int H) {
    int i = blockIdx.x * blockDim.x + threadIdx.x;
    if (i < H) {
        float sc = g[i] * rsqrtf(v[i] + 1e-5f);
        s[i] = sc;
        t[i] = (b[i] - m[i]) * sc + be[i];
    }
}

// W[K,F] f32 -> Wt[F,K] bf16
__global__ void k_w2bf(const float* __restrict__ W, u16* __restrict__ Wt, int K, int F) {
    int i = blockIdx.x * blockDim.x + threadIdx.x;
    if (i < K * F) {
        int k = i / F, f = i % F;
        Wt[(size_t)f * K + k] = f2bf(W[i]);
    }
}

// x f32 -> bf16
__global__ void k_x2bf(const float* __restrict__ x, u16* __restrict__ xb, int n4) {
    int i = blockIdx.x * blockDim.x + threadIdx.x;
    if (i < n4) {
        float4 v = *(const float4*)(x + (size_t)i * 4);
        us4 o;
        o.x = f2bf(v.x); o.y = f2bf(v.y); o.z = f2bf(v.z); o.w = f2bf(v.w);
        *(us4*)(xb + (size_t)i * 4) = o;
    }
}

// ---------------- MFMA GEMM ----------------
// C[M,Ftot] = A_bf16[M,K] @ Wt_bf16[Ftot,K]^T, no LDS, direct fragment loads.
// MODE 0: f32 store. MODE 1: BN+ReLU bf16 store. MODE 2: plain bf16 store.
template<int K, int FT, int MODE>
__global__ __launch_bounds__(256) void g_mfma(const u16* __restrict__ A,
                                              const u16* __restrict__ Wt,
                                              void* __restrict__ Cv, int M, int Ftot,
                                              const float* __restrict__ s,
                                              const float* __restrict__ t) {
    int tid = threadIdx.x;
    int w = tid >> 6, l = tid & 63;
    int row0 = blockIdx.x * 64;
    int col0 = blockIdx.y * FT;
    int lr = l & 15;
    int koff = (l >> 4) * 8;

    int arow = row0 + w * 16 + lr;
    int arow_ld = (arow < M) ? arow : 0;
    const u16* ap = A + (size_t)arow_ld * K + koff;
    const u16* wp = Wt + (size_t)(col0 + lr) * K + koff;

    constexpr int NF = FT / 16;
    f32x4 acc[NF];
    #pragma unroll
    for (int c = 0; c < NF; ++c) acc[c] = (f32x4){0.f, 0.f, 0.f, 0.f};

    #pragma unroll
    for (int kk = 0; kk < K / 32; ++kk) {
        bfx8 af = *(const bfx8*)(ap + kk * 32);
        #pragma unroll
        for (int c = 0; c < NF; ++c) {
            bfx8 bf = *(const bfx8*)(wp + (size_t)c * 16 * K + kk * 32);
            acc[c] = __builtin_amdgcn_mfma_f32_16x16x32_bf16(af, bf, acc[c], 0, 0, 0);
        }
    }

    int orow = row0 + w * 16 + (l >> 4) * 4;
    if (MODE == 1) {
        u16* C = (u16*)Cv;
        #pragma unroll
        for (int c = 0; c < NF; ++c) {
            int gc = col0 + c * 16 + lr;
            float sc = s[gc], tc = t[gc];
            #pragma unroll
            for (int r = 0; r < 4; ++r) {
                int gr = orow + r;
                if (gr < M)
                    C[(size_t)gr * Ftot + gc] = f2bf(fmaxf(acc[c][r] * sc + tc, 0.f));
            }
        }
    } else if (MODE == 2) {
        u16* C = (u16*)Cv;
        #pragma unroll
        for (int c = 0; c < NF; ++c) {
            int gc = col0 + c * 16 + lr;
            #pragma unroll
            for (int r = 0; r < 4; ++r) {
                int gr = orow + r;
                if (gr < M) C[(size_t)gr * Ftot + gc] = f2bf(acc[c][r]);
            }
        }
    } else {
        float* C = (float*)Cv;
        #pragma unroll
        for (int c = 0; c < NF; ++c) {
            int gc = col0 + c * 16 + lr;
            #pragma unroll
            for (int r = 0; r < 4; ++r) {
                int gr = orow + r;
                if (gr < M) C[(size_t)gr * Ftot + gc] = acc[c][r];
            }
        }
    }
}

// ---------------- Aggregation ----------------
// agg_x: F=128 bf16. 32 lanes/node, lane owns 4 features (8B). 2 nodes/wave.
__global__ __launch_bounds__(256) void agg_x(const u16* __restrict__ in,
                                             u16* __restrict__ outp,
                                             const int* __restrict__ row_ptr,
                                             const int* __restrict__ csr_src,
                                             const float* __restrict__ csr_coef,
                                             const float* __restrict__ dinv,
                                             int nnodes) {
    int tid = threadIdx.x;
    int wv = tid >> 6, lane = tid & 63;
    int half = lane >> 5, l32 = lane & 31;
    int node = (blockIdx.x * 4 + wv) * 2 + half;
    if (node >= nnodes) return;
    int off = l32 * 4;
    const u16* bp = in + off;
    float d = dinv[node];
    float dd = d * d;
    us4 su = *(const us4*)(in + (size_t)node * 128 + off);
    float a0 = bf2f(su.x) * dd, a1 = bf2f(su.y) * dd, a2 = bf2f(su.z) * dd, a3 = bf2f(su.w) * dd;
    int e = row_ptr[node], e1 = row_ptr[node + 1];
    for (; e + 4 <= e1; e += 4) {
        int s0 = csr_src[e], s1 = csr_src[e + 1], s2 = csr_src[e + 2], s3 = csr_src[e + 3];
        float c0 = csr_coef[e], c1 = csr_coef[e + 1], c2 = csr_coef[e + 2], c3 = csr_coef[e + 3];
        us4 v0 = *(const us4*)(bp + (size_t)s0 * 128);
        us4 v1 = *(const us4*)(bp + (size_t)s1 * 128);
        us4 v2 = *(const us4*)(bp + (size_t)s2 * 128);
        us4 v3 = *(const us4*)(bp + (size_t)s3 * 128);
        a0 += c0 * bf2f(v0.x) + c1 * bf2f(v1.x) + c2 * bf2f(v2.x) + c3 * bf2f(v3.x);
        a1 += c0 * bf2f(v0.y) + c1 * bf2f(v1.y) + c2 * bf2f(v2.y) + c3 * bf2f(v3.y);
        a2 += c0 * bf2f(v0.z) + c1 * bf2f(v1.z) + c2 * bf2f(v2.z) + c3 * bf2f(v3.z);
        a3 += c0 * bf2f(v0.w) + c1 * bf2f(v1.w) + c2 * bf2f(v2.w) + c3 * bf2f(v3.w);
    }
    for (; e < e1; ++e) {
        int s0 = csr_src[e];
        float c0 = csr_coef[e];
        us4 v0 = *(const us4*)(bp + (size_t)s0 * 128);
        a0 += c0 * bf2f(v0.x); a1 += c0 * bf2f(v0.y);
        a2 += c0 * bf2f(v0.z); a3 += c0 * bf2f(v0.w);
    }
    us4 o;
    o.x = f2bf(a0); o.y = f2bf(a1); o.z = f2bf(a2); o.w = f2bf(a3);
    *(us4*)(outp + (size_t)node * 128 + off) = o;
}

// agg_h: F=256 bf16. 32 lanes/node, lane owns 8 features (16B). 2 nodes/wave.
__global__ __launch_bounds__(256) void agg_h(const u16* __restrict__ in,
                                             u16* __restrict__ outp,
                                             const int* __restrict__ row_ptr,
                                             const int* __restrict__ csr_src,
                                             const float* __restrict__ csr_coef,
                                             const float* __restrict__ dinv,
                                             int nnodes) {
    int tid = threadIdx.x;
    int wv = tid >> 6, lane = tid & 63;
    int half = lane >> 5, l32 = lane & 31;
    int node = (blockIdx.x * 4 + wv) * 2 + half;
    if (node >= nnodes) return;
    int off = l32 * 8;
    const u16* bp = in + off;
    float d = dinv[node];
    float dd = d * d;
    float acc[8];
    us8 su = *(const us8*)(in + (size_t)node * 256 + off);
    #pragma unroll
    for (int j = 0; j < 8; ++j) acc[j] = bf2f(su[j]) * dd;
    int e = row_ptr[node], e1 = row_ptr[node + 1];
    for (; e + 4 <= e1; e += 4) {
        int s0 = csr_src[e], s1 = csr_src[e + 1], s2 = csr_src[e + 2], s3 = csr_src[e + 3];
        float c0 = csr_coef[e], c1 = csr_coef[e + 1], c2 = csr_coef[e + 2], c3 = csr_coef[e + 3];
        us8 v0 = *(const us8*)(bp + (size_t)s0 * 256);
        us8 v1 = *(const us8*)(bp + (size_t)s1 * 256);
        us8 v2 = *(const us8*)(bp + (size_t)s2 * 256);
        us8 v3 = *(const us8*)(bp + (size_t)s3 * 256);
        #pragma unroll
        for (int j = 0; j < 8; ++j)
            acc[j] += c0 * bf2f(v0[j]) + c1 * bf2f(v1[j]) + c2 * bf2f(v2[j]) + c3 * bf2f(v3[j]);
    }
    for (; e < e1; ++e) {
        int s0 = csr_src[e];
        float c0 = csr_coef[e];
        us8 v0 = *(const us8*)(bp + (size_t)s0 * 256);
        #pragma unroll
        for (int j = 0; j < 8; ++j) acc[j] += c0 * bf2f(v0[j]);
    }
    us8 o;
    #pragma unroll
    for (int j = 0; j < 8; ++j) o[j] = f2bf(acc[j]);
    *(us8*)(outp + (size_t)node * 256 + off) = o;
}

// agg32: F=32 bf16 in, f32 sigmoid out. 32 lanes/node, 2 nodes/wave.
__global__ __launch_bounds__(256) void agg32_sig(const u16* __restrict__ z,
                                                 float* __restrict__ out,
                                                 const int* __restrict__ row_ptr,
                                                 const int* __restrict__ csr_src,
                                                 const float* __restrict__ csr_coef,
                                                 const float* __restrict__ dinv,
                                                 const float* __restrict__ b3,
                                                 int nnodes) {
    int tid = threadIdx.x;
    int wv = tid >> 6, lane = tid & 63;
    int half = lane >> 5, l32 = lane & 31;
    int node = (blockIdx.x * 4 + wv) * 2 + half;
    if (node >= nnodes) return;
    float d = dinv[node];
    float acc = bf2f(z[(size_t)node * 32 + l32]) * d * d;
    int e = row_ptr[node], e1 = row_ptr[node + 1];
    for (; e + 4 <= e1; e += 4) {
        int s0 = csr_src[e], s1 = csr_src[e + 1], s2 = csr_src[e + 2], s3 = csr_src[e + 3];
        float c0 = csr_coef[e], c1 = csr_coef[e + 1], c2 = csr_coef[e + 2], c3 = csr_coef[e + 3];
        float z0 = bf2f(z[(size_t)s0 * 32 + l32]);
        float z1 = bf2f(z[(size_t)s1 * 32 + l32]);
        float z2 = bf2f(z[(size_t)s2 * 32 + l32]);
        float z3v = bf2f(z[(size_t)s3 * 32 + l32]);
        acc += c0 * z0 + c1 * z1 + c2 * z2 + c3 * z3v;
    }
    for (; e < e1; ++e) {
        acc += csr_coef[e] * bf2f(z[(size_t)csr_src[e] * 32 + l32]);
    }
    acc += b3[l32];
    out[(size_t)node * 32 + l32] = 1.f / (1.f + expf(-acc));
}

// ---------------- launch ----------------

extern "C" void kernel_launch(void* const* d_in, const int* in_sizes, int n_in,
                              void* d_out, int out_size, void* d_ws, size_t ws_size,
                              hipStream_t stream) {
    const float* x  = (const float*)d_in[0];
    const int*   ei = (const int*)d_in[1];
    const float* W1 = (const float*)d_in[2];
    const float* b1 = (const float*)d_in[3];
    const float* g1 = (const float*)d_in[4];
    const float* be1 = (const float*)d_in[5];
    const float* m1 = (const float*)d_in[6];
    const float* v1 = (const float*)d_in[7];
    const float* W2 = (const float*)d_in[8];
    const float* b2 = (const float*)d_in[9];
    const float* g2 = (const float*)d_in[10];
    const float* be2 = (const float*)d_in[11];
    const float* m2 = (const float*)d_in[12];
    const float* v2 = (const float*)d_in[13];
    const float* W3 = (const float*)d_in[14];
    const float* b3 = (const float*)d_in[15];
    float* out = (float*)d_out;

    const int N = in_sizes[0] / 128;   // 100000
    const int E = in_sizes[1] / 2;     // 1600000

    char* w = (char*)d_ws;
    auto alloc = [&](size_t bytes) -> void* {
        void* p = (void*)w;
        w += (bytes + 255) & ~(size_t)255;
        return p;
    };
    int* cnt      = (int*)alloc((size_t)N * 4);
    int* row_ptr  = (int*)alloc((size_t)(N + 1) * 4);
    int* cursor   = (int*)alloc((size_t)N * 4);
    float* dinv   = (float*)alloc((size_t)N * 4);
    int* partials = (int*)alloc(256 * 4);
    int* blkoff   = (int*)alloc(256 * 4);
    float* s1 = (float*)alloc(256 * 4);
    float* t1 = (float*)alloc(256 * 4);
    float* s2 = (float*)alloc(256 * 4);
    float* t2 = (float*)alloc(256 * 4);
    u16* Wt1 = (u16*)alloc((size_t)128 * 256 * 2);
    u16* Wt2 = (u16*)alloc((size_t)256 * 256 * 2);
    u16* Wt3 = (u16*)alloc((size_t)256 * 32 * 2);
    int* csr_src    = (int*)alloc((size_t)E * 4);
    float* csr_coef = (float*)alloc((size_t)E * 4);
    u16* xbf  = (u16*)alloc((size_t)N * 128 * 2);   // x bf16; later reused as z3 (bf16, N*32)
    u16* bufA = (u16*)alloc((size_t)N * 256 * 2);
    u16* bufB = (u16*)alloc((size_t)N * 256 * 2);
    u16* z3 = xbf;   // N*32 bf16 = 6.4MB <= 25.6MB, xbf dead after layer 1

    int nb = (N + 511) / 512;
    int gx = (N + 63) / 64;
    int gagg = (N + 7) / 8;   // 8 nodes per block (4 waves x 2)

    // CSR build
    k_zero_int<<<(N + 255) / 256, 256, 0, stream>>>(cnt, N);
    k_count<<<(E + 255) / 256, 256, 0, stream>>>(ei, cnt, E);
    k_partial<<<nb, 256, 0, stream>>>(cnt, partials, N);
    k_scan_top<<<1, 256, 0, stream>>>(partials, blkoff, nb);
    k_apply<<<nb, 512, 0, stream>>>(cnt, blkoff, row_ptr, cursor, dinv, N, E);
    k_scatter<<<(E + 255) / 256, 256, 0, stream>>>(ei, cursor, csr_src, csr_coef, dinv, E);

    // param prep
    k_bnfold<<<1, 256, 0, stream>>>(b1, g1, be1, m1, v1, s1, t1, 256);
    k_bnfold<<<1, 256, 0, stream>>>(b2, g2, be2, m2, v2, s2, t2, 256);
    k_w2bf<<<(128 * 256 + 255) / 256, 256, 0, stream>>>(W1, Wt1, 128, 256);
    k_w2bf<<<(256 * 256 + 255) / 256, 256, 0, stream>>>(W2, Wt2, 256, 256);
    k_w2bf<<<(256 * 32 + 255) / 256, 256, 0, stream>>>(W3, Wt3, 256, 32);
    k_x2bf<<<(N * 128 / 4 + 255) / 256, 256, 0, stream>>>(x, xbf, N * 128 / 4);

    // Layer 1
    agg_x<<<gagg, 256, 0, stream>>>(xbf, bufA, row_ptr, csr_src, csr_coef, dinv, N);
    g_mfma<128, 64, 1><<<dim3(gx, 4), 256, 0, stream>>>(bufA, Wt1, bufB, N, 256, s1, t1);

    // Layer 2
    agg_h<<<gagg, 256, 0, stream>>>(bufB, bufA, row_ptr, csr_src, csr_coef, dinv, N);
    g_mfma<256, 64, 1><<<dim3(gx, 4), 256, 0, stream>>>(bufA, Wt2, bufB, N, 256, s2, t2);

    // Layer 3: GEMM(256->32) -> bf16, then aggregate(32) + b3 + sigmoid
    g_mfma<256, 32, 2><<<dim3(gx, 1), 256, 0, stream>>>(bufB, Wt3, (void*)z3, N, 32,
                                                        (const float*)nullptr,
                                                        (const float*)nullptr);
    agg32_sig<<<gagg, 256, 0, stream>>>(z3, out, row_ptr, csr_src, csr_coef, dinv, b3, N);
}